// Round 10
// baseline (260.276 us; speedup 1.0000x reference)
//
#include <hip/hip_runtime.h>
#include <math.h>

#define N_NODES 16384
#define N_EDGES 262144
#define IN_DIM  512
#define HID     256
#define HEADS   4
#define NBATCH  64
#define ACTIONS 32
#define NEG_SLOPE 0.2f

typedef __attribute__((ext_vector_type(8))) short short8;
typedef __attribute__((ext_vector_type(4))) float f32x4;

__device__ __forceinline__ float lrelu(float v) { return v > 0.f ? v : NEG_SLOPE * v; }

__device__ __forceinline__ unsigned short bf16_rne(float f) {
    union { float f; unsigned int u; } x; x.f = f;
    unsigned int u = x.u;
    unsigned int r = (u + 0x7FFFu + ((u >> 16) & 1u)) >> 16;
    return (unsigned short)r;
}

__device__ __forceinline__ float bf16_to_f32(unsigned short s) {
    union { unsigned int u; float f; } x; x.u = (unsigned int)s << 16;
    return x.f;
}

__device__ __forceinline__ float4 bf4_to_f4(ushort4 u) {
    return make_float4(bf16_to_f32(u.x), bf16_to_f32(u.y), bf16_to_f32(u.z), bf16_to_f32(u.w));
}

__device__ __forceinline__ void async_copy16(const unsigned short* g, unsigned short* l) {
    __builtin_amdgcn_global_load_lds(
        (const __attribute__((address_space(1))) unsigned int*)g,
        (__attribute__((address_space(3))) unsigned int*)l, 16, 0, 0);
}

// ---------------------------------------------------------------- fused setup
#define NB_CONV 8192
#define NB_WLR  1024
#define NB_WSTK 1024
#define NB_WATT 8
#define NB_ZERO 128
#define NB_SETUP (NB_CONV + NB_WLR + NB_WSTK + NB_WATT + NB_ZERO)

__global__ __launch_bounds__(256) void setup_kernel(
        const float* __restrict__ x, unsigned short* __restrict__ xb,
        const float* __restrict__ wl, const float* __restrict__ wr, unsigned short* __restrict__ bt1,
        const float* __restrict__ gat_w, unsigned short* __restrict__ bt2,
        const float* __restrict__ att_src, const float* __restrict__ att_dst, float* __restrict__ watt,
        int* __restrict__ deg, float* __restrict__ pooled) {
    int bid = blockIdx.x, tid = threadIdx.x;
    if (bid < NB_CONV) {
        int i = (bid * 256 + tid) * 4;
        float4 v = *(const float4*)(x + i);
        ushort4 o;
        o.x = bf16_rne(v.x); o.y = bf16_rne(v.y); o.z = bf16_rne(v.z); o.w = bf16_rne(v.w);
        *(ushort4*)(xb + i) = o;
    } else if (bid < NB_CONV + NB_WLR) {
        int idx = (bid - NB_CONV) * 256 + tid;
        int j = idx >> 9;
        int k = idx & 511;
        float v = (j < HID) ? wl[k * HID + j] : wr[k * HID + (j - HID)];
        bt1[idx] = bf16_rne(v);
    } else if (bid < NB_CONV + NB_WLR + NB_WSTK) {
        int idx = (bid - NB_CONV - NB_WLR) * 256 + tid;
        int c = idx >> 10;
        int r = idx & 1023;
        int h = r >> 8;
        int k = r & 255;
        bt2[idx] = bf16_rne(gat_w[(size_t)k * (HEADS * HID) + h * HID + c]);
    } else if (bid < NB_CONV + NB_WLR + NB_WSTK + NB_WATT) {
        int j = bid - NB_CONV - NB_WLR - NB_WSTK;
        int c = tid;
        int hh = j & 3;
        const float* att = (j < 4) ? (att_src + hh * HID) : (att_dst + hh * HID);
        float s = 0.f;
        for (int cc = 0; cc < HID; cc++)
            s += gat_w[(size_t)c * (HEADS * HID) + hh * HID + cc] * att[cc];
        watt[j * HID + c] = s;
    } else {
        int idx = (bid - NB_CONV - NB_WLR - NB_WSTK - NB_WATT) * 256 + tid;
        if (idx < N_NODES) deg[idx] = 0;
        else pooled[idx - N_NODES] = 0.f;
    }
}

// ---------------------------------------------------------------- CSR build
__global__ void deg_kernel(const int* __restrict__ ei, int* __restrict__ deg) {
    int e = blockIdx.x * 256 + threadIdx.x;
    if (e < N_EDGES) atomicAdd(&deg[ei[N_EDGES + e]], 1);
}

__global__ __launch_bounds__(256) void scan_kernel(const int* __restrict__ deg,
                                                   int* __restrict__ row_start,
                                                   int* __restrict__ pos) {
    int t = threadIdx.x;
    int lane = t & 63, wv = t >> 6;
    int base = t * 64;
    int4 buf[16];
    int sum = 0;
#pragma unroll
    for (int i = 0; i < 16; i++) {
        buf[i] = ((const int4*)(deg + base))[i];
        sum += buf[i].x + buf[i].y + buf[i].z + buf[i].w;
    }
    int v = sum;
#pragma unroll
    for (int off = 1; off < 64; off <<= 1) {
        int u = __shfl_up(v, off);
        if (lane >= off) v += u;
    }
    __shared__ int wsum[4];
    if (lane == 63) wsum[wv] = v;
    __syncthreads();
    int wbase = 0;
    for (int w0 = 0; w0 < wv; w0++) wbase += wsum[w0];
    int run = wbase + v - sum;
#pragma unroll
    for (int i = 0; i < 16; i++) {
        int4 b = buf[i];
        int4 o;
        o.x = run; run += b.x;
        o.y = run; run += b.y;
        o.z = run; run += b.z;
        o.w = run; run += b.w;
        ((int4*)(row_start + base))[i] = o;
        ((int4*)(pos + base))[i] = o;
    }
    if (t == 255) row_start[N_NODES] = run;
}

__global__ void fill_kernel(const int* __restrict__ ei, int* __restrict__ pos,
                            int* __restrict__ col) {
    int e = blockIdx.x * 256 + threadIdx.x;
    if (e < N_EDGES) {
        int s = ei[e];
        int d = ei[N_EDGES + e];
        int p = atomicAdd(&pos[d], 1);
        col[p] = s;
    }
}

// ---------------------------------------------------------------- GEMM1: 64x128 tile, dual-slab BK=2x32
#define BK 32

__global__ __launch_bounds__(256) void gemm1_kernel(const unsigned short* __restrict__ A,
                                                    const unsigned short* __restrict__ Bt,
                                                    unsigned short* __restrict__ Cb,
                                                    int Nn, int K) {
    __shared__ __align__(16) unsigned short As[2][64 * BK];
    __shared__ __align__(16) unsigned short Bs[2][128 * BK];

    int tid  = threadIdx.x;
    int wv   = tid >> 6;
    int lane = tid & 63;
    int m0 = blockIdx.y * 64;
    int n0 = blockIdx.x * 128;
    int wm = (wv & 1) * 32;
    int wn = (wv >> 1) * 64;

    int srow = tid >> 2;
    int scol = (tid & 3) * 8;
    const unsigned short* Ag  = A  + (size_t)(m0 + srow) * K + scol;
    const unsigned short* Bg0 = Bt + (size_t)(n0 + srow) * K + scol;
    const unsigned short* Bg1 = Bt + (size_t)(n0 + 64 + srow) * K + scol;

    int fr = lane & 15;
    int fk = (lane >> 4) * 8;
    f32x4 acc[2][4] = {};

    for (int kt = 0; kt < K; kt += 2 * BK) {
#pragma unroll
        for (int s = 0; s < 2; s++) {
            int ko = kt + s * BK;
            async_copy16(Ag + ko,  &As[s][wv * 512]);
            async_copy16(Bg0 + ko, &Bs[s][wv * 512]);
            async_copy16(Bg1 + ko, &Bs[s][2048 + wv * 512]);
        }
        __syncthreads();

#pragma unroll
        for (int s = 0; s < 2; s++) {
            short8 af[2], bf[4];
#pragma unroll
            for (int mi = 0; mi < 2; mi++)
                af[mi] = *(const short8*)&As[s][(wm + mi * 16 + fr) * BK + fk];
#pragma unroll
            for (int ni = 0; ni < 4; ni++)
                bf[ni] = *(const short8*)&Bs[s][(wn + ni * 16 + fr) * BK + fk];
#pragma unroll
            for (int mi = 0; mi < 2; mi++)
#pragma unroll
                for (int ni = 0; ni < 4; ni++)
                    acc[mi][ni] = __builtin_amdgcn_mfma_f32_16x16x32_bf16(af[mi], bf[ni], acc[mi][ni], 0, 0, 0);
        }
        __syncthreads();
    }

    int cr = (lane >> 4) * 4;
    int cc = lane & 15;
#pragma unroll
    for (int mi = 0; mi < 2; mi++) {
#pragma unroll
        for (int ni = 0; ni < 4; ni++) {
            int gc = n0 + wn + ni * 16 + cc;
#pragma unroll
            for (int r = 0; r < 4; r++) {
                int gr = m0 + wm + mi * 16 + cr + r;
                Cb[(size_t)gr * Nn + gc] = bf16_rne(acc[mi][ni][r]);
            }
        }
    }
}

// ---------------------------------------------------------------- GEMM2: 64x64 tile, dual-slab BK=2x32, fused pool
__global__ __launch_bounds__(256) void gemm2_pool_kernel(const unsigned short* __restrict__ A,
                                                         const unsigned short* __restrict__ Bt,
                                                         const int* __restrict__ batch,
                                                         const float* __restrict__ bias,
                                                         float scale,
                                                         float* __restrict__ pooled,
                                                         int Nn, int K) {
    __shared__ __align__(16) unsigned short As[2][64 * BK];
    __shared__ __align__(16) unsigned short Bs[2][64 * BK];
    __shared__ int bsh[64];

    int tid  = threadIdx.x;
    int wv   = tid >> 6;
    int lane = tid & 63;
    int m0 = blockIdx.y * 64;
    int n0 = blockIdx.x * 64;
    int wm = (wv & 1) * 32;
    int wn = (wv >> 1) * 32;

    if (tid < 64) bsh[tid] = batch[m0 + tid];

    int srow = tid >> 2;
    int scol = (tid & 3) * 8;
    const unsigned short* Ag = A  + (size_t)(m0 + srow) * K + scol;
    const unsigned short* Bg = Bt + (size_t)(n0 + srow) * K + scol;

    int fr = lane & 15;
    int fk = (lane >> 4) * 8;
    f32x4 acc[2][2] = {};

    for (int kt = 0; kt < K; kt += 2 * BK) {
#pragma unroll
        for (int s = 0; s < 2; s++) {
            int ko = kt + s * BK;
            async_copy16(Ag + ko, &As[s][wv * 512]);
            async_copy16(Bg + ko, &Bs[s][wv * 512]);
        }
        __syncthreads();

#pragma unroll
        for (int s = 0; s < 2; s++) {
            short8 af[2], bf[2];
#pragma unroll
            for (int mi = 0; mi < 2; mi++)
                af[mi] = *(const short8*)&As[s][(wm + mi * 16 + fr) * BK + fk];
#pragma unroll
            for (int ni = 0; ni < 2; ni++)
                bf[ni] = *(const short8*)&Bs[s][(wn + ni * 16 + fr) * BK + fk];
#pragma unroll
            for (int mi = 0; mi < 2; mi++)
#pragma unroll
                for (int ni = 0; ni < 2; ni++)
                    acc[mi][ni] = __builtin_amdgcn_mfma_f32_16x16x32_bf16(af[mi], bf[ni], acc[mi][ni], 0, 0, 0);
        }
        __syncthreads();
    }

    int cr = (lane >> 4) * 4;
    int cc = lane & 15;
#pragma unroll
    for (int mi = 0; mi < 2; mi++) {
        int rowb = wm + mi * 16 + cr;
        int b0 = bsh[rowb], b3 = bsh[rowb + 3];
#pragma unroll
        for (int ni = 0; ni < 2; ni++) {
            int gc = n0 + wn + ni * 16 + cc;
            float b = bias[gc];
            float v0 = fmaxf(fmaf(acc[mi][ni][0], scale, b), 0.f);
            float v1 = fmaxf(fmaf(acc[mi][ni][1], scale, b), 0.f);
            float v2 = fmaxf(fmaf(acc[mi][ni][2], scale, b), 0.f);
            float v3 = fmaxf(fmaf(acc[mi][ni][3], scale, b), 0.f);
            if (b0 == b3) {
                atomicAdd(&pooled[b0 * HID + gc], (v0 + v1) + (v2 + v3));
            } else {
                atomicAdd(&pooled[bsh[rowb + 0] * HID + gc], v0);
                atomicAdd(&pooled[bsh[rowb + 1] * HID + gc], v1);
                atomicAdd(&pooled[bsh[rowb + 2] * HID + gc], v2);
                atomicAdd(&pooled[bsh[rowb + 3] * HID + gc], v3);
            }
        }
    }
}

// ---------------------------------------------------------------- SAGE aggregation (8x-unrolled gather)
__global__ __launch_bounds__(256) void sage_agg_kernel(const unsigned short* __restrict__ xlr,
                                                       const int* __restrict__ row_start,
                                                       const int* __restrict__ col,
                                                       const float* __restrict__ b_l,
                                                       const float* __restrict__ watt,
                                                       unsigned short* __restrict__ hb,
                                                       float* __restrict__ a_att) {
    __shared__ float watt_s[8 * HID];
    for (int i = threadIdx.x; i < 8 * HID; i += 256) watt_s[i] = watt[i];
    __syncthreads();

    int wave = threadIdx.x >> 6;
    int lane = threadIdx.x & 63;
    int n = blockIdx.x * 4 + wave;
    int start = row_start[n], end = row_start[n + 1];
    int c0 = lane * 4;

    float4 acc = make_float4(0.f, 0.f, 0.f, 0.f);
    int e = start;
    for (; e + 8 <= end; e += 8) {
        ushort4 u[8];
#pragma unroll
        for (int q = 0; q < 8; q++) {
            int s = col[e + q];
            u[q] = *(const ushort4*)(xlr + (size_t)s * IN_DIM + c0);
        }
#pragma unroll
        for (int q = 0; q < 8; q++) {
            float4 v = bf4_to_f4(u[q]);
            acc.x += v.x; acc.y += v.y; acc.z += v.z; acc.w += v.w;
        }
    }
    for (; e + 4 <= end; e += 4) {
        int s0 = col[e], s1 = col[e + 1], s2 = col[e + 2], s3 = col[e + 3];
        ushort4 u0 = *(const ushort4*)(xlr + (size_t)s0 * IN_DIM + c0);
        ushort4 u1 = *(const ushort4*)(xlr + (size_t)s1 * IN_DIM + c0);
        ushort4 u2 = *(const ushort4*)(xlr + (size_t)s2 * IN_DIM + c0);
        ushort4 u3 = *(const ushort4*)(xlr + (size_t)s3 * IN_DIM + c0);
        float4 v0 = bf4_to_f4(u0), v1 = bf4_to_f4(u1), v2 = bf4_to_f4(u2), v3 = bf4_to_f4(u3);
        acc.x += (v0.x + v1.x) + (v2.x + v3.x);
        acc.y += (v0.y + v1.y) + (v2.y + v3.y);
        acc.z += (v0.z + v1.z) + (v2.z + v3.z);
        acc.w += (v0.w + v1.w) + (v2.w + v3.w);
    }
    for (; e < end; e++) {
        int s = col[e];
        float4 v = bf4_to_f4(*(const ushort4*)(xlr + (size_t)s * IN_DIM + c0));
        acc.x += v.x; acc.y += v.y; acc.z += v.z; acc.w += v.w;
    }
    float inv = 1.f / (float)max(end - start, 1);
    float4 xr = bf4_to_f4(*(const ushort4*)(xlr + (size_t)n * IN_DIM + HID + c0));
    float4 bl = *(const float4*)(b_l + c0);
    float4 hv;
    hv.x = fmaxf(fmaf(acc.x, inv, bl.x + xr.x), 0.f);
    hv.y = fmaxf(fmaf(acc.y, inv, bl.y + xr.y), 0.f);
    hv.z = fmaxf(fmaf(acc.z, inv, bl.z + xr.z), 0.f);
    hv.w = fmaxf(fmaf(acc.w, inv, bl.w + xr.w), 0.f);
    ushort4 ho;
    ho.x = bf16_rne(hv.x); ho.y = bf16_rne(hv.y); ho.z = bf16_rne(hv.z); ho.w = bf16_rne(hv.w);
    *(ushort4*)(hb + (size_t)n * HID + c0) = ho;

    float p[8];
#pragma unroll
    for (int j = 0; j < 8; j++) {
        float4 wt = *(const float4*)&watt_s[j * HID + c0];
        p[j] = hv.x * wt.x + hv.y * wt.y + hv.z * wt.z + hv.w * wt.w;
    }
#pragma unroll
    for (int off = 32; off; off >>= 1)
#pragma unroll
        for (int j = 0; j < 8; j++) p[j] += __shfl_down(p[j], off);
    if (lane == 0) {
#pragma unroll
        for (int j = 0; j < 8; j++) a_att[n * 8 + j] = p[j];
    }
}

// ---------------------------------------------------------------- GAT: single-sweep softmax + 4x-unrolled aggregation
__global__ __launch_bounds__(256) void gat_agg_kernel(const unsigned short* __restrict__ hb,
                                                      const float* __restrict__ a_att,
                                                      const int* __restrict__ row_start,
                                                      const int* __restrict__ col,
                                                      unsigned short* __restrict__ T) {
    __shared__ __align__(16) float w_s[4][64 * 4];
    int wave = threadIdx.x >> 6;
    int lane = threadIdx.x & 63;
    int n = blockIdx.x * 4 + wave;
    int start = row_start[n], end = row_start[n + 1];

    float4 an = *(const float4*)(a_att + n * 8);
    float4 ad = *(const float4*)(a_att + n * 8 + 4);
    float adst[4] = {ad.x, ad.y, ad.z, ad.w};
    float selfl[4] = {lrelu(an.x + ad.x), lrelu(an.y + ad.y), lrelu(an.z + ad.z), lrelu(an.w + ad.w)};
    float m[4], wself[4];
#pragma unroll
    for (int hh = 0; hh < 4; hh++) {
        m[hh] = fmaxf(selfl[hh], 0.f);
        wself[hh] = __expf(selfl[hh] - m[hh]);
    }

    int c0 = lane * 4;
    float4 hn = bf4_to_f4(*(const ushort4*)(hb + (size_t)n * HID + c0));
    float4 acc[4];
#pragma unroll
    for (int hh = 0; hh < 4; hh++)
        acc[hh] = make_float4(wself[hh] * hn.x, wself[hh] * hn.y, wself[hh] * hn.z, wself[hh] * hn.w);

    float dpart[4] = {0.f, 0.f, 0.f, 0.f};

    for (int base = start; base < end; base += 64) {
        int cnt = min(64, end - base);
        if (lane < cnt) {
            int s = col[base + lane];
            float4 as = *(const float4*)(a_att + s * 8);
            float4 wv;
            wv.x = __expf(lrelu(as.x + adst[0]) - m[0]);
            wv.y = __expf(lrelu(as.y + adst[1]) - m[1]);
            wv.z = __expf(lrelu(as.z + adst[2]) - m[2]);
            wv.w = __expf(lrelu(as.w + adst[3]) - m[3]);
            *(float4*)&w_s[wave][lane * 4] = wv;
            dpart[0] += wv.x; dpart[1] += wv.y; dpart[2] += wv.z; dpart[3] += wv.w;
        }
        __builtin_amdgcn_wave_barrier();

        int i = 0;
        for (; i + 4 <= cnt; i += 4) {
            ushort4 u[4];
            float4 wq[4];
#pragma unroll
            for (int q = 0; q < 4; q++) {
                int s = col[base + i + q];
                u[q]  = *(const ushort4*)(hb + (size_t)s * HID + c0);
                wq[q] = *(const float4*)&w_s[wave][(i + q) * 4];
            }
#pragma unroll
            for (int q = 0; q < 4; q++) {
                float4 hq = bf4_to_f4(u[q]);
                float wr[4] = {wq[q].x, wq[q].y, wq[q].z, wq[q].w};
#pragma unroll
                for (int hh = 0; hh < 4; hh++) {
                    acc[hh].x = fmaf(wr[hh], hq.x, acc[hh].x);
                    acc[hh].y = fmaf(wr[hh], hq.y, acc[hh].y);
                    acc[hh].z = fmaf(wr[hh], hq.z, acc[hh].z);
                    acc[hh].w = fmaf(wr[hh], hq.w, acc[hh].w);
                }
            }
        }
        for (; i < cnt; i++) {
            int s0 = col[base + i];
            float4 w0 = *(const float4*)&w_s[wave][i * 4];
            float4 h0 = bf4_to_f4(*(const ushort4*)(hb + (size_t)s0 * HID + c0));
            float wr0[4] = {w0.x, w0.y, w0.z, w0.w};
#pragma unroll
            for (int hh = 0; hh < 4; hh++) {
                acc[hh].x = fmaf(wr0[hh], h0.x, acc[hh].x);
                acc[hh].y = fmaf(wr0[hh], h0.y, acc[hh].y);
                acc[hh].z = fmaf(wr0[hh], h0.z, acc[hh].z);
                acc[hh].w = fmaf(wr0[hh], h0.w, acc[hh].w);
            }
        }
        __builtin_amdgcn_wave_barrier();
    }

#pragma unroll
    for (int off = 32; off; off >>= 1)
#pragma unroll
        for (int hh = 0; hh < 4; hh++) dpart[hh] += __shfl_down(dpart[hh], off);
    float invd[4];
#pragma unroll
    for (int hh = 0; hh < 4; hh++)
        invd[hh] = 1.f / (__shfl(dpart[hh], 0) + wself[hh]);

#pragma unroll
    for (int hh = 0; hh < 4; hh++) {
        ushort4 o;
        o.x = bf16_rne(acc[hh].x * invd[hh]); o.y = bf16_rne(acc[hh].y * invd[hh]);
        o.z = bf16_rne(acc[hh].z * invd[hh]); o.w = bf16_rne(acc[hh].w * invd[hh]);
        *(ushort4*)(T + (size_t)n * (HEADS * HID) + hh * HID + c0) = o;
    }
}

// ---------------------------------------------------------------- head
__device__ __forceinline__ int lower_bound_i(const int* a, int n, int v) {
    int lo = 0, hi = n;
    while (lo < hi) {
        int mid = (lo + hi) >> 1;
        if (a[mid] < v) lo = mid + 1; else hi = mid;
    }
    return lo;
}

__global__ __launch_bounds__(256) void head_kernel(const float* __restrict__ pooled,
                                                   const int* __restrict__ batch,
                                                   const float* __restrict__ head_w,
                                                   const float* __restrict__ head_b,
                                                   float* __restrict__ out) {
    __shared__ float sm[HID];
    int b = blockIdx.x;
    int c = threadIdx.x;
    int lo = lower_bound_i(batch, N_NODES, b);
    int hi = lower_bound_i(batch, N_NODES, b + 1);
    int cnt = hi - lo;
    sm[c] = pooled[b * HID + c] / (float)max(cnt, 1);
    __syncthreads();
    if (c < ACTIONS) {
        float acc = head_b[c];
        for (int k = 0; k < HID; k++) acc = fmaf(sm[k], head_w[k * ACTIONS + c], acc);
        out[b * ACTIONS + c] = acc;
    }
}

// ---------------------------------------------------------------- launcher
extern "C" void kernel_launch(void* const* d_in, const int* in_sizes, int n_in,
                              void* d_out, int out_size, void* d_ws, size_t ws_size,
                              hipStream_t stream) {
    const float* x        = (const float*)d_in[0];
    const int*   ei       = (const int*)d_in[1];
    const int*   batch    = (const int*)d_in[2];
    const float* sage_w_l = (const float*)d_in[3];
    const float* sage_b_l = (const float*)d_in[4];
    const float* sage_w_r = (const float*)d_in[5];
    const float* gat_w    = (const float*)d_in[6];
    const float* att_src  = (const float*)d_in[7];
    const float* att_dst  = (const float*)d_in[8];
    const float* gat_b    = (const float*)d_in[9];
    const float* head_w   = (const float*)d_in[10];
    const float* head_b   = (const float*)d_in[11];
    float* out = (float*)d_out;

    char* w = (char*)d_ws;
    float* a_att  = (float*)w; w += (size_t)N_NODES * 8 * 4;
    float* watt   = (float*)w; w += (size_t)8 * HID * 4;
    float* pooled = (float*)w; w += (size_t)NBATCH * HID * 4;
    unsigned short* xb  = (unsigned short*)w; w += (size_t)N_NODES * IN_DIM * 2;
    unsigned short* xlr = (unsigned short*)w; w += (size_t)N_NODES * IN_DIM * 2;
    unsigned short* hb  = (unsigned short*)w; w += (size_t)N_NODES * HID * 2;
    unsigned short* T   = (unsigned short*)w; w += (size_t)N_NODES * HEADS * HID * 2;
    unsigned short* bt1 = (unsigned short*)w; w += (size_t)(2 * HID) * IN_DIM * 2;
    unsigned short* bt2 = (unsigned short*)w; w += (size_t)HID * (HEADS * HID) * 2;
    int* deg      = (int*)w;   w += (size_t)N_NODES * 4;
    int* row_start= (int*)w;   w += (size_t)(N_NODES + 64) * 4;
    int* pos      = (int*)w;   w += (size_t)N_NODES * 4;
    int* col      = (int*)w;   w += (size_t)N_EDGES * 4;

    setup_kernel<<<NB_SETUP, 256, 0, stream>>>(x, xb, sage_w_l, sage_w_r, bt1,
                                               gat_w, bt2, att_src, att_dst, watt,
                                               deg, pooled);

    deg_kernel<<<N_EDGES / 256, 256, 0, stream>>>(ei, deg);
    scan_kernel<<<1, 256, 0, stream>>>(deg, row_start, pos);
    fill_kernel<<<N_EDGES / 256, 256, 0, stream>>>(ei, pos, col);

    gemm1_kernel<<<dim3((2 * HID) / 128, N_NODES / 64), 256, 0, stream>>>(
        xb, bt1, xlr, 2 * HID, IN_DIM);

    sage_agg_kernel<<<N_NODES / 4, 256, 0, stream>>>(xlr, row_start, col, sage_b_l, watt, hb, a_att);

    gat_agg_kernel<<<N_NODES / 4, 256, 0, stream>>>(hb, a_att, row_start, col, T);

    gemm2_pool_kernel<<<dim3(HID / 64, N_NODES / 64), 256, 0, stream>>>(
        T, bt2, batch, gat_b, 0.25f, pooled, HID, HEADS * HID);

    head_kernel<<<NBATCH, 256, 0, stream>>>(pooled, batch, head_w, head_b, out);
}

// Round 11
// 257.733 us; speedup vs baseline: 1.0099x; 1.0099x over previous
//
#include <hip/hip_runtime.h>
#include <math.h>

#define N_NODES 16384
#define N_EDGES 262144
#define IN_DIM  512
#define HID     256
#define HEADS   4
#define NBATCH  64
#define ACTIONS 32
#define NEG_SLOPE 0.2f

typedef __attribute__((ext_vector_type(8))) short short8;
typedef __attribute__((ext_vector_type(4))) float f32x4;

__device__ __forceinline__ float lrelu(float v) { return v > 0.f ? v : NEG_SLOPE * v; }

__device__ __forceinline__ unsigned short bf16_rne(float f) {
    union { float f; unsigned int u; } x; x.f = f;
    unsigned int u = x.u;
    unsigned int r = (u + 0x7FFFu + ((u >> 16) & 1u)) >> 16;
    return (unsigned short)r;
}

__device__ __forceinline__ float bf16_to_f32(unsigned short s) {
    union { unsigned int u; float f; } x; x.u = (unsigned int)s << 16;
    return x.f;
}

__device__ __forceinline__ float4 bf4_to_f4(ushort4 u) {
    return make_float4(bf16_to_f32(u.x), bf16_to_f32(u.y), bf16_to_f32(u.z), bf16_to_f32(u.w));
}

__device__ __forceinline__ void async_copy16(const unsigned short* g, unsigned short* l) {
    __builtin_amdgcn_global_load_lds(
        (const __attribute__((address_space(1))) unsigned int*)g,
        (__attribute__((address_space(3))) unsigned int*)l, 16, 0, 0);
}

// ---------------------------------------------------------------- fused setup (no x conversion — fused into gemm1)
#define NB_WLR  1024
#define NB_WSTK 1024
#define NB_WATT 8
#define NB_ZERO 128
#define NB_SETUP (NB_WLR + NB_WSTK + NB_WATT + NB_ZERO)

__global__ __launch_bounds__(256) void setup_kernel(
        const float* __restrict__ wl, const float* __restrict__ wr, unsigned short* __restrict__ bt1,
        const float* __restrict__ gat_w, unsigned short* __restrict__ bt2,
        const float* __restrict__ att_src, const float* __restrict__ att_dst, float* __restrict__ watt,
        int* __restrict__ deg, float* __restrict__ pooled) {
    int bid = blockIdx.x, tid = threadIdx.x;
    if (bid < NB_WLR) {
        int idx = bid * 256 + tid;
        int j = idx >> 9;
        int k = idx & 511;
        float v = (j < HID) ? wl[k * HID + j] : wr[k * HID + (j - HID)];
        bt1[idx] = bf16_rne(v);
    } else if (bid < NB_WLR + NB_WSTK) {
        int idx = (bid - NB_WLR) * 256 + tid;
        int c = idx >> 10;
        int r = idx & 1023;
        int h = r >> 8;
        int k = r & 255;
        bt2[idx] = bf16_rne(gat_w[(size_t)k * (HEADS * HID) + h * HID + c]);
    } else if (bid < NB_WLR + NB_WSTK + NB_WATT) {
        int j = bid - NB_WLR - NB_WSTK;
        int c = tid;
        int hh = j & 3;
        const float* att = (j < 4) ? (att_src + hh * HID) : (att_dst + hh * HID);
        float s = 0.f;
        for (int cc = 0; cc < HID; cc++)
            s += gat_w[(size_t)c * (HEADS * HID) + hh * HID + cc] * att[cc];
        watt[j * HID + c] = s;
    } else {
        int idx = (bid - NB_WLR - NB_WSTK - NB_WATT) * 256 + tid;
        if (idx < N_NODES) deg[idx] = 0;
        else pooled[idx - N_NODES] = 0.f;
    }
}

// ---------------------------------------------------------------- CSR build
__global__ void deg_kernel(const int* __restrict__ ei, int* __restrict__ deg) {
    int e = blockIdx.x * 256 + threadIdx.x;
    if (e < N_EDGES) atomicAdd(&deg[ei[N_EDGES + e]], 1);
}

__global__ __launch_bounds__(256) void scan_kernel(const int* __restrict__ deg,
                                                   int* __restrict__ row_start,
                                                   int* __restrict__ pos) {
    int t = threadIdx.x;
    int lane = t & 63, wv = t >> 6;
    int base = t * 64;
    int4 buf[16];
    int sum = 0;
#pragma unroll
    for (int i = 0; i < 16; i++) {
        buf[i] = ((const int4*)(deg + base))[i];
        sum += buf[i].x + buf[i].y + buf[i].z + buf[i].w;
    }
    int v = sum;
#pragma unroll
    for (int off = 1; off < 64; off <<= 1) {
        int u = __shfl_up(v, off);
        if (lane >= off) v += u;
    }
    __shared__ int wsum[4];
    if (lane == 63) wsum[wv] = v;
    __syncthreads();
    int wbase = 0;
    for (int w0 = 0; w0 < wv; w0++) wbase += wsum[w0];
    int run = wbase + v - sum;
#pragma unroll
    for (int i = 0; i < 16; i++) {
        int4 b = buf[i];
        int4 o;
        o.x = run; run += b.x;
        o.y = run; run += b.y;
        o.z = run; run += b.z;
        o.w = run; run += b.w;
        ((int4*)(row_start + base))[i] = o;
        ((int4*)(pos + base))[i] = o;
    }
    if (t == 255) row_start[N_NODES] = run;
}

__global__ void fill_kernel(const int* __restrict__ ei, int* __restrict__ pos,
                            int* __restrict__ col) {
    int e = blockIdx.x * 256 + threadIdx.x;
    if (e < N_EDGES) {
        int s = ei[e];
        int d = ei[N_EDGES + e];
        int p = atomicAdd(&pos[d], 1);
        col[p] = s;
    }
}

// ---------------------------------------------------------------- GEMM1: 64x128 tile, dual-slab BK=2x32
// A staged directly from fp32 x with fused bf16 conversion (same LDS layout as async path).
#define BK 32

__global__ __launch_bounds__(256) void gemm1_kernel(const float* __restrict__ X,
                                                    const unsigned short* __restrict__ Bt,
                                                    unsigned short* __restrict__ Cb,
                                                    int Nn, int K) {
    __shared__ __align__(16) unsigned short As[2][64 * BK];
    __shared__ __align__(16) unsigned short Bs[2][128 * BK];

    int tid  = threadIdx.x;
    int wv   = tid >> 6;
    int lane = tid & 63;
    int m0 = blockIdx.y * 64;
    int n0 = blockIdx.x * 128;
    int wm = (wv & 1) * 32;
    int wn = (wv >> 1) * 64;

    int srow = tid >> 2;            // 0..63
    int scol = (tid & 3) * 8;       // 0,8,16,24
    const float*          Xg  = X  + (size_t)(m0 + srow) * K + scol;
    const unsigned short* Bg0 = Bt + (size_t)(n0 + srow) * K + scol;
    const unsigned short* Bg1 = Bt + (size_t)(n0 + 64 + srow) * K + scol;

    int fr = lane & 15;
    int fk = (lane >> 4) * 8;
    f32x4 acc[2][4] = {};

    for (int kt = 0; kt < K; kt += 2 * BK) {
#pragma unroll
        for (int s = 0; s < 2; s++) {
            int ko = kt + s * BK;
            // B: async global->LDS
            async_copy16(Bg0 + ko, &Bs[s][wv * 512]);
            async_copy16(Bg1 + ko, &Bs[s][2048 + wv * 512]);
            // A: fp32 load + convert + LDS store (same slot async would use: elem tid*8)
            float4 a0 = *(const float4*)(Xg + ko);
            float4 a1 = *(const float4*)(Xg + ko + 4);
            short8 p;
            p[0] = (short)bf16_rne(a0.x); p[1] = (short)bf16_rne(a0.y);
            p[2] = (short)bf16_rne(a0.z); p[3] = (short)bf16_rne(a0.w);
            p[4] = (short)bf16_rne(a1.x); p[5] = (short)bf16_rne(a1.y);
            p[6] = (short)bf16_rne(a1.z); p[7] = (short)bf16_rne(a1.w);
            *(short8*)&As[s][srow * BK + scol] = p;
        }
        __syncthreads();

#pragma unroll
        for (int s = 0; s < 2; s++) {
            short8 af[2], bf[4];
#pragma unroll
            for (int mi = 0; mi < 2; mi++)
                af[mi] = *(const short8*)&As[s][(wm + mi * 16 + fr) * BK + fk];
#pragma unroll
            for (int ni = 0; ni < 4; ni++)
                bf[ni] = *(const short8*)&Bs[s][(wn + ni * 16 + fr) * BK + fk];
#pragma unroll
            for (int mi = 0; mi < 2; mi++)
#pragma unroll
                for (int ni = 0; ni < 4; ni++)
                    acc[mi][ni] = __builtin_amdgcn_mfma_f32_16x16x32_bf16(af[mi], bf[ni], acc[mi][ni], 0, 0, 0);
        }
        __syncthreads();
    }

    int cr = (lane >> 4) * 4;
    int cc = lane & 15;
#pragma unroll
    for (int mi = 0; mi < 2; mi++) {
#pragma unroll
        for (int ni = 0; ni < 4; ni++) {
            int gc = n0 + wn + ni * 16 + cc;
#pragma unroll
            for (int r = 0; r < 4; r++) {
                int gr = m0 + wm + mi * 16 + cr + r;
                Cb[(size_t)gr * Nn + gc] = bf16_rne(acc[mi][ni][r]);
            }
        }
    }
}

// ---------------------------------------------------------------- GEMM2: 64x64 tile, dual-slab BK=2x32, fused pool
__global__ __launch_bounds__(256) void gemm2_pool_kernel(const unsigned short* __restrict__ A,
                                                         const unsigned short* __restrict__ Bt,
                                                         const int* __restrict__ batch,
                                                         const float* __restrict__ bias,
                                                         float scale,
                                                         float* __restrict__ pooled,
                                                         int Nn, int K) {
    __shared__ __align__(16) unsigned short As[2][64 * BK];
    __shared__ __align__(16) unsigned short Bs[2][64 * BK];
    __shared__ int bsh[64];

    int tid  = threadIdx.x;
    int wv   = tid >> 6;
    int lane = tid & 63;
    int m0 = blockIdx.y * 64;
    int n0 = blockIdx.x * 64;
    int wm = (wv & 1) * 32;
    int wn = (wv >> 1) * 32;

    if (tid < 64) bsh[tid] = batch[m0 + tid];

    int srow = tid >> 2;
    int scol = (tid & 3) * 8;
    const unsigned short* Ag = A  + (size_t)(m0 + srow) * K + scol;
    const unsigned short* Bg = Bt + (size_t)(n0 + srow) * K + scol;

    int fr = lane & 15;
    int fk = (lane >> 4) * 8;
    f32x4 acc[2][2] = {};

    for (int kt = 0; kt < K; kt += 2 * BK) {
#pragma unroll
        for (int s = 0; s < 2; s++) {
            int ko = kt + s * BK;
            async_copy16(Ag + ko, &As[s][wv * 512]);
            async_copy16(Bg + ko, &Bs[s][wv * 512]);
        }
        __syncthreads();

#pragma unroll
        for (int s = 0; s < 2; s++) {
            short8 af[2], bf[2];
#pragma unroll
            for (int mi = 0; mi < 2; mi++)
                af[mi] = *(const short8*)&As[s][(wm + mi * 16 + fr) * BK + fk];
#pragma unroll
            for (int ni = 0; ni < 2; ni++)
                bf[ni] = *(const short8*)&Bs[s][(wn + ni * 16 + fr) * BK + fk];
#pragma unroll
            for (int mi = 0; mi < 2; mi++)
#pragma unroll
                for (int ni = 0; ni < 2; ni++)
                    acc[mi][ni] = __builtin_amdgcn_mfma_f32_16x16x32_bf16(af[mi], bf[ni], acc[mi][ni], 0, 0, 0);
        }
        __syncthreads();
    }

    int cr = (lane >> 4) * 4;
    int cc = lane & 15;
#pragma unroll
    for (int mi = 0; mi < 2; mi++) {
        int rowb = wm + mi * 16 + cr;
        int b0 = bsh[rowb], b3 = bsh[rowb + 3];
#pragma unroll
        for (int ni = 0; ni < 2; ni++) {
            int gc = n0 + wn + ni * 16 + cc;
            float b = bias[gc];
            float v0 = fmaxf(fmaf(acc[mi][ni][0], scale, b), 0.f);
            float v1 = fmaxf(fmaf(acc[mi][ni][1], scale, b), 0.f);
            float v2 = fmaxf(fmaf(acc[mi][ni][2], scale, b), 0.f);
            float v3 = fmaxf(fmaf(acc[mi][ni][3], scale, b), 0.f);
            if (b0 == b3) {
                atomicAdd(&pooled[b0 * HID + gc], (v0 + v1) + (v2 + v3));
            } else {
                atomicAdd(&pooled[bsh[rowb + 0] * HID + gc], v0);
                atomicAdd(&pooled[bsh[rowb + 1] * HID + gc], v1);
                atomicAdd(&pooled[bsh[rowb + 2] * HID + gc], v2);
                atomicAdd(&pooled[bsh[rowb + 3] * HID + gc], v3);
            }
        }
    }
}

// ---------------------------------------------------------------- SAGE aggregation (R9-proven 4x unroll)
__global__ __launch_bounds__(256) void sage_agg_kernel(const unsigned short* __restrict__ xlr,
                                                       const int* __restrict__ row_start,
                                                       const int* __restrict__ col,
                                                       const float* __restrict__ b_l,
                                                       const float* __restrict__ watt,
                                                       unsigned short* __restrict__ hb,
                                                       float* __restrict__ a_att) {
    __shared__ float watt_s[8 * HID];
    for (int i = threadIdx.x; i < 8 * HID; i += 256) watt_s[i] = watt[i];
    __syncthreads();

    int wave = threadIdx.x >> 6;
    int lane = threadIdx.x & 63;
    int n = blockIdx.x * 4 + wave;
    int start = row_start[n], end = row_start[n + 1];
    int c0 = lane * 4;

    float4 acc = make_float4(0.f, 0.f, 0.f, 0.f);
    int e = start;
    for (; e + 4 <= end; e += 4) {
        int s0 = col[e], s1 = col[e + 1], s2 = col[e + 2], s3 = col[e + 3];
        ushort4 u0 = *(const ushort4*)(xlr + (size_t)s0 * IN_DIM + c0);
        ushort4 u1 = *(const ushort4*)(xlr + (size_t)s1 * IN_DIM + c0);
        ushort4 u2 = *(const ushort4*)(xlr + (size_t)s2 * IN_DIM + c0);
        ushort4 u3 = *(const ushort4*)(xlr + (size_t)s3 * IN_DIM + c0);
        float4 v0 = bf4_to_f4(u0), v1 = bf4_to_f4(u1), v2 = bf4_to_f4(u2), v3 = bf4_to_f4(u3);
        acc.x += (v0.x + v1.x) + (v2.x + v3.x);
        acc.y += (v0.y + v1.y) + (v2.y + v3.y);
        acc.z += (v0.z + v1.z) + (v2.z + v3.z);
        acc.w += (v0.w + v1.w) + (v2.w + v3.w);
    }
    for (; e < end; e++) {
        int s = col[e];
        float4 v = bf4_to_f4(*(const ushort4*)(xlr + (size_t)s * IN_DIM + c0));
        acc.x += v.x; acc.y += v.y; acc.z += v.z; acc.w += v.w;
    }
    float inv = 1.f / (float)max(end - start, 1);
    float4 xr = bf4_to_f4(*(const ushort4*)(xlr + (size_t)n * IN_DIM + HID + c0));
    float4 bl = *(const float4*)(b_l + c0);
    float4 hv;
    hv.x = fmaxf(fmaf(acc.x, inv, bl.x + xr.x), 0.f);
    hv.y = fmaxf(fmaf(acc.y, inv, bl.y + xr.y), 0.f);
    hv.z = fmaxf(fmaf(acc.z, inv, bl.z + xr.z), 0.f);
    hv.w = fmaxf(fmaf(acc.w, inv, bl.w + xr.w), 0.f);
    ushort4 ho;
    ho.x = bf16_rne(hv.x); ho.y = bf16_rne(hv.y); ho.z = bf16_rne(hv.z); ho.w = bf16_rne(hv.w);
    *(ushort4*)(hb + (size_t)n * HID + c0) = ho;

    float p[8];
#pragma unroll
    for (int j = 0; j < 8; j++) {
        float4 wt = *(const float4*)&watt_s[j * HID + c0];
        p[j] = hv.x * wt.x + hv.y * wt.y + hv.z * wt.z + hv.w * wt.w;
    }
#pragma unroll
    for (int off = 32; off; off >>= 1)
#pragma unroll
        for (int j = 0; j < 8; j++) p[j] += __shfl_down(p[j], off);
    if (lane == 0) {
#pragma unroll
        for (int j = 0; j < 8; j++) a_att[n * 8 + j] = p[j];
    }
}

// ---------------------------------------------------------------- GAT: single-sweep softmax + aggregation (R9-proven)
__global__ __launch_bounds__(256) void gat_agg_kernel(const unsigned short* __restrict__ hb,
                                                      const float* __restrict__ a_att,
                                                      const int* __restrict__ row_start,
                                                      const int* __restrict__ col,
                                                      unsigned short* __restrict__ T) {
    __shared__ __align__(16) float w_s[4][64 * 4];
    int wave = threadIdx.x >> 6;
    int lane = threadIdx.x & 63;
    int n = blockIdx.x * 4 + wave;
    int start = row_start[n], end = row_start[n + 1];

    float4 an = *(const float4*)(a_att + n * 8);
    float4 ad = *(const float4*)(a_att + n * 8 + 4);
    float adst[4] = {ad.x, ad.y, ad.z, ad.w};
    float selfl[4] = {lrelu(an.x + ad.x), lrelu(an.y + ad.y), lrelu(an.z + ad.z), lrelu(an.w + ad.w)};
    float m[4], wself[4];
#pragma unroll
    for (int hh = 0; hh < 4; hh++) {
        m[hh] = fmaxf(selfl[hh], 0.f);
        wself[hh] = __expf(selfl[hh] - m[hh]);
    }

    int c0 = lane * 4;
    float4 hn = bf4_to_f4(*(const ushort4*)(hb + (size_t)n * HID + c0));
    float4 acc[4];
#pragma unroll
    for (int hh = 0; hh < 4; hh++)
        acc[hh] = make_float4(wself[hh] * hn.x, wself[hh] * hn.y, wself[hh] * hn.z, wself[hh] * hn.w);

    float dpart[4] = {0.f, 0.f, 0.f, 0.f};

    for (int base = start; base < end; base += 64) {
        int cnt = min(64, end - base);
        if (lane < cnt) {
            int s = col[base + lane];
            float4 as = *(const float4*)(a_att + s * 8);
            float4 wv;
            wv.x = __expf(lrelu(as.x + adst[0]) - m[0]);
            wv.y = __expf(lrelu(as.y + adst[1]) - m[1]);
            wv.z = __expf(lrelu(as.z + adst[2]) - m[2]);
            wv.w = __expf(lrelu(as.w + adst[3]) - m[3]);
            *(float4*)&w_s[wave][lane * 4] = wv;
            dpart[0] += wv.x; dpart[1] += wv.y; dpart[2] += wv.z; dpart[3] += wv.w;
        }
        __builtin_amdgcn_wave_barrier();

        int i = 0;
        for (; i + 2 <= cnt; i += 2) {
            int s0 = col[base + i], s1 = col[base + i + 1];
            float4 w0 = *(const float4*)&w_s[wave][i * 4];
            float4 w1 = *(const float4*)&w_s[wave][(i + 1) * 4];
            ushort4 u0 = *(const ushort4*)(hb + (size_t)s0 * HID + c0);
            ushort4 u1 = *(const ushort4*)(hb + (size_t)s1 * HID + c0);
            float4 h0 = bf4_to_f4(u0), h1 = bf4_to_f4(u1);
            float wr0[4] = {w0.x, w0.y, w0.z, w0.w};
            float wr1[4] = {w1.x, w1.y, w1.z, w1.w};
#pragma unroll
            for (int hh = 0; hh < 4; hh++) {
                acc[hh].x = fmaf(wr0[hh], h0.x, fmaf(wr1[hh], h1.x, acc[hh].x));
                acc[hh].y = fmaf(wr0[hh], h0.y, fmaf(wr1[hh], h1.y, acc[hh].y));
                acc[hh].z = fmaf(wr0[hh], h0.z, fmaf(wr1[hh], h1.z, acc[hh].z));
                acc[hh].w = fmaf(wr0[hh], h0.w, fmaf(wr1[hh], h1.w, acc[hh].w));
            }
        }
        if (i < cnt) {
            int s0 = col[base + i];
            float4 w0 = *(const float4*)&w_s[wave][i * 4];
            float4 h0 = bf4_to_f4(*(const ushort4*)(hb + (size_t)s0 * HID + c0));
            float wr0[4] = {w0.x, w0.y, w0.z, w0.w};
#pragma unroll
            for (int hh = 0; hh < 4; hh++) {
                acc[hh].x = fmaf(wr0[hh], h0.x, acc[hh].x);
                acc[hh].y = fmaf(wr0[hh], h0.y, acc[hh].y);
                acc[hh].z = fmaf(wr0[hh], h0.z, acc[hh].z);
                acc[hh].w = fmaf(wr0[hh], h0.w, acc[hh].w);
            }
        }
        __builtin_amdgcn_wave_barrier();
    }

#pragma unroll
    for (int off = 32; off; off >>= 1)
#pragma unroll
        for (int hh = 0; hh < 4; hh++) dpart[hh] += __shfl_down(dpart[hh], off);
    float invd[4];
#pragma unroll
    for (int hh = 0; hh < 4; hh++)
        invd[hh] = 1.f / (__shfl(dpart[hh], 0) + wself[hh]);

#pragma unroll
    for (int hh = 0; hh < 4; hh++) {
        ushort4 o;
        o.x = bf16_rne(acc[hh].x * invd[hh]); o.y = bf16_rne(acc[hh].y * invd[hh]);
        o.z = bf16_rne(acc[hh].z * invd[hh]); o.w = bf16_rne(acc[hh].w * invd[hh]);
        *(ushort4*)(T + (size_t)n * (HEADS * HID) + hh * HID + c0) = o;
    }
}

// ---------------------------------------------------------------- head
__device__ __forceinline__ int lower_bound_i(const int* a, int n, int v) {
    int lo = 0, hi = n;
    while (lo < hi) {
        int mid = (lo + hi) >> 1;
        if (a[mid] < v) lo = mid + 1; else hi = mid;
    }
    return lo;
}

__global__ __launch_bounds__(256) void head_kernel(const float* __restrict__ pooled,
                                                   const int* __restrict__ batch,
                                                   const float* __restrict__ head_w,
                                                   const float* __restrict__ head_b,
                                                   float* __restrict__ out) {
    __shared__ float sm[HID];
    int b = blockIdx.x;
    int c = threadIdx.x;
    int lo = lower_bound_i(batch, N_NODES, b);
    int hi = lower_bound_i(batch, N_NODES, b + 1);
    int cnt = hi - lo;
    sm[c] = pooled[b * HID + c] / (float)max(cnt, 1);
    __syncthreads();
    if (c < ACTIONS) {
        float acc = head_b[c];
        for (int k = 0; k < HID; k++) acc = fmaf(sm[k], head_w[k * ACTIONS + c], acc);
        out[b * ACTIONS + c] = acc;
    }
}

// ---------------------------------------------------------------- launcher
extern "C" void kernel_launch(void* const* d_in, const int* in_sizes, int n_in,
                              void* d_out, int out_size, void* d_ws, size_t ws_size,
                              hipStream_t stream) {
    const float* x        = (const float*)d_in[0];
    const int*   ei       = (const int*)d_in[1];
    const int*   batch    = (const int*)d_in[2];
    const float* sage_w_l = (const float*)d_in[3];
    const float* sage_b_l = (const float*)d_in[4];
    const float* sage_w_r = (const float*)d_in[5];
    const float* gat_w    = (const float*)d_in[6];
    const float* att_src  = (const float*)d_in[7];
    const float* att_dst  = (const float*)d_in[8];
    const float* gat_b    = (const float*)d_in[9];
    const float* head_w   = (const float*)d_in[10];
    const float* head_b   = (const float*)d_in[11];
    float* out = (float*)d_out;

    char* w = (char*)d_ws;
    float* a_att  = (float*)w; w += (size_t)N_NODES * 8 * 4;
    float* watt   = (float*)w; w += (size_t)8 * HID * 4;
    float* pooled = (float*)w; w += (size_t)NBATCH * HID * 4;
    unsigned short* xlr = (unsigned short*)w; w += (size_t)N_NODES * IN_DIM * 2;
    unsigned short* hb  = (unsigned short*)w; w += (size_t)N_NODES * HID * 2;
    unsigned short* T   = (unsigned short*)w; w += (size_t)N_NODES * HEADS * HID * 2;
    unsigned short* bt1 = (unsigned short*)w; w += (size_t)(2 * HID) * IN_DIM * 2;
    unsigned short* bt2 = (unsigned short*)w; w += (size_t)HID * (HEADS * HID) * 2;
    int* deg      = (int*)w;   w += (size_t)N_NODES * 4;
    int* row_start= (int*)w;   w += (size_t)(N_NODES + 64) * 4;
    int* pos      = (int*)w;   w += (size_t)N_NODES * 4;
    int* col      = (int*)w;   w += (size_t)N_EDGES * 4;

    setup_kernel<<<NB_SETUP, 256, 0, stream>>>(sage_w_l, sage_w_r, bt1,
                                               gat_w, bt2, att_src, att_dst, watt,
                                               deg, pooled);

    deg_kernel<<<N_EDGES / 256, 256, 0, stream>>>(ei, deg);
    scan_kernel<<<1, 256, 0, stream>>>(deg, row_start, pos);
    fill_kernel<<<N_EDGES / 256, 256, 0, stream>>>(ei, pos, col);

    // xlr = x @ [W_l | W_r]  (fp32 A staged with fused bf16 conversion)
    gemm1_kernel<<<dim3((2 * HID) / 128, N_NODES / 64), 256, 0, stream>>>(
        x, bt1, xlr, 2 * HID, IN_DIM);

    sage_agg_kernel<<<N_NODES / 4, 256, 0, stream>>>(xlr, row_start, col, sage_b_l, watt, hb, a_att);

    gat_agg_kernel<<<N_NODES / 4, 256, 0, stream>>>(hb, a_att, row_start, col, T);

    gemm2_pool_kernel<<<dim3(HID / 64, N_NODES / 64), 256, 0, stream>>>(
        T, bt2, batch, gat_b, 0.25f, pooled, HID, HEADS * HID);

    head_kernel<<<NBATCH, 256, 0, stream>>>(pooled, batch, head_w, head_b, out);
}